// Round 14
// baseline (359.940 us; speedup 1.0000x reference)
//
#include <hip/hip_runtime.h>

// ---------------------------------------------------------------------------
// SLAYER-style spiking CNN forward pass, MI355X.  Round 11 (resubmit; bench
// failed on GPU acquisition timeout — never measured).
//
// psp (SRM alpha kernel) as double-exponential IIR cascade (exact):
//   g1[t] = x[t] + a*g1[t-1]; g2[t] = g1[t] + a*g2[t-1]; u = (e/tau)*(g2-g1)
//
// R11: TAIL round (conv2v/conv1w untouched — clean attribution).  The rest
//   is 241 us vs conv2v's 104: psp5 ran 52 blocks on 256 CUs (80% idle),
//   dense2 was a 410-deep single-accumulator f64 chain on 125 blocks,
//   psp6 ran 2 blocks.
//   - dense2 -> k_dense2m: exact i8-limb MFMA GEMM (M=3200,N=10pad32,
//     K=410pad416; 13 chunks x 5 limbs = 65 MFMAs/wave; 25 blocks), with
//     k_limbs3 packing wf2 (same verified limb scheme as dense1/conv2).
//   - s5 stride 410 -> 416 (psp5 zeroes the pad) so dense2m A-fragments
//     are single 16B loads.
//   - psp5: 64-thread blocks -> 208 blocks spread across CUs.
//   - psp6: 64-thread blocks -> 5 blocks.
// ---------------------------------------------------------------------------

namespace {
constexpr int B = 32, T = 100;
constexpr double A1 = 0.90483741803595957;  // exp(-1/10)
constexpr double CE = 0.27182818284590452;  // e/10
constexpr double SC39 = 549755813888.0;     // 2^39
constexpr double INV39 = 1.0 / 549755813888.0;

// workspace byte offsets
constexpr size_t OFF_M1 = 0;                                  // u32 [B*T][28]
constexpr size_t OFF_M2 = OFF_M1 + (size_t)B * T * 28 * 4;    // u32 [B*T][16][14]
constexpr size_t OFF_S4 = OFF_M2 + (size_t)B * T * 224 * 4;   // u8  [B*T][1568]
constexpr size_t OFF_D5 = OFF_S4 + (size_t)B * T * 1568;      // f64 [B*T][410]
constexpr size_t OFF_S5 = OFF_D5 + (size_t)B * T * 410 * 8;   // u8  [B*T][416]
constexpr size_t OFF_D6 = OFF_S5 + (size_t)B * T * 416;       // f64 [B*T][10]
constexpr size_t OFF_BP = OFF_D6 + (size_t)B * T * 10 * 8;    // i8  [13][5][49][64][16]
constexpr size_t OFF_BP2 = OFF_BP + (size_t)13 * 5 * 49 * 64 * 16;  // i8 [5][13][64][16]
// A_pack (conv2 limbs) aliases the d5 region: written by k_limbs, read by
// k_conv2v, both complete before k_dense1m writes d5 (stream-ordered).
constexpr size_t OFF_AP = OFF_D5;
}  // namespace

using i32x4 = __attribute__((ext_vector_type(4))) int;
using i32x16 = __attribute__((ext_vector_type(16))) int;

// Stage 0: rate encode + bit-pack rows.  Thread per (b,y,t); loops x.
__global__ void k_encode_pack(const float* __restrict__ img, const float* __restrict__ ru,
                              unsigned int* __restrict__ m1) {
  int i = blockIdx.x * 256 + threadIdx.x;
  if (i >= B * 28 * T) return;
  int t = i % T;
  int y = (i / T) % 28;
  int b = i / (T * 28);
  unsigned int m = 0;
  const float* rb = ru + ((size_t)b * 784 + y * 28) * T + t;
  const float* ib = img + b * 784 + y * 28;
  for (int x = 0; x < 28; x++) {
    m |= (rb[(size_t)x * T] < ib[x]) ? (1u << x) : 0u;
  }
  m1[((size_t)b * T + t) * 28 + y] = m;
}

// Stage 1 fused: conv1 (1->16,5x5,pad2) + psp + spike + pool2 + psp + spike.
// (unchanged from R9)
__global__ __launch_bounds__(256) void k_conv1w(const unsigned int* __restrict__ m1,
                                                const float* __restrict__ w1,
                                                unsigned int* __restrict__ m2) {
  __shared__ double lut2[320 * 2];       // [dy*64+f][j]; 5120 B
  __shared__ unsigned int mrow[2][32];   // rows iy=-2..29 at idx iy+2; guards 0
  int o = blockIdx.x % 16, b = blockIdx.x / 16;
  int tid = threadIdx.x;
  for (int e = tid; e < 320; e += 256) {
    int dy = e / 64, f = e % 64;
    const float* wb = w1 + o * 25 + dy * 5;
    double v0 = 0.0, v1 = 0.0;
#pragma unroll
    for (int dx = 0; dx < 5; dx++) {
      double wv = (double)wb[dx];
      if ((f >> dx) & 1) v0 += wv;
      if ((f >> (dx + 1)) & 1) v1 += wv;
    }
    lut2[e * 2 + 0] = v0;
    lut2[e * 2 + 1] = v1;
  }
  if (tid < 32) {
    mrow[0][tid] = 0;
    mrow[1][tid] = 0;
  }
  int py = tid >> 4, px = tid & 15;
  bool act = (px < 14) && (py < 14);
  int yA = 2 * py, xA = 2 * px;
  double g1[4] = {0, 0, 0, 0}, g2[4] = {0, 0, 0, 0};
  double q1 = 0.0, q2 = 0.0;
  const unsigned int* m1b = m1 + (size_t)b * T * 28;
  if (tid < 28) mrow[0][tid + 2] = m1b[tid] << 2;
  __syncthreads();
  for (int t = 0; t < T; t++) {
    int p = t & 1, np = p ^ 1;
    bool dold = (tid < 28) && (t + 1 < T);
    unsigned int ldv = 0;
    if (dold) ldv = m1b[(t + 1) * 28 + tid] << 2;
    unsigned int poolBit = 0;
    if (act) {
      double sAa = 0, sAb = 0, sBa = 0, sBb = 0;
      const unsigned int* mc = mrow[p];
#pragma unroll
      for (int dy = 0; dy < 5; dy++) {
        unsigned int mA = mc[yA + dy];
        unsigned int mB = mc[yA + 1 + dy];
        const double* eA = lut2 + (dy * 64 + (int)((mA >> xA) & 63u)) * 2;
        const double* eB = lut2 + (dy * 64 + (int)((mB >> xA) & 63u)) * 2;
        sAa += eA[0];
        sAb += eA[1];
        sBa += eB[0];
        sBb += eB[1];
      }
      g1[0] = sAa + A1 * g1[0]; g2[0] = g1[0] + A1 * g2[0];
      g1[1] = sAb + A1 * g1[1]; g2[1] = g1[1] + A1 * g2[1];
      g1[2] = sBa + A1 * g1[2]; g2[2] = g1[2] + A1 * g2[2];
      g1[3] = sBb + A1 * g1[3]; g2[3] = g1[3] + A1 * g2[3];
      int s0 = (CE * (g2[0] - g1[0]) >= 1.0) ? 1 : 0;
      int s1 = (CE * (g2[1] - g1[1]) >= 1.0) ? 1 : 0;
      int s2 = (CE * (g2[2] - g1[2]) >= 1.0) ? 1 : 0;
      int s3 = (CE * (g2[3] - g1[3]) >= 1.0) ? 1 : 0;
      double s = 1.1 * (double)(s0 + s1 + s2 + s3);
      q1 = s + A1 * q1;
      q2 = q1 + A1 * q2;
      poolBit = (CE * (q2 - q1) >= 1.0) ? 1u : 0u;
    }
    unsigned long long bal = __ballot((int)poolBit);
    if (act && px == 0) {
      int lane = tid & 63;
      unsigned int rm = (unsigned int)((bal >> (lane & 48)) & 0x3FFFull);
      m2[((size_t)(b * T + t) * 16 + o) * 14 + py] = rm;
    }
    if (dold) mrow[np][tid + 2] = ldv;
    __syncthreads();
  }
}

// conv2 weight limbs: 5 signed base-256 digits of round(w2*2^39), laid out as
// MFMA A-fragments.  (unchanged — layout verified bit-exact)
__global__ void k_limbs(const float* __restrict__ w2, signed char* __restrict__ AP) {
  int i = blockIdx.x * 256 + threadIdx.x;
  if (i >= 32 * 80 * 8) return;
  int dx = i & 7;
  int g = (i >> 3) % 80;
  int o = i / 640;
  int c = g >> 2, r = g & 3, eh = r >> 1, kh = r & 1;
  int lane = kh * 32 + o, e = eh * 8 + dx;
  int ci = g / 5, dy = g % 5;
  float wv = (dx < 5) ? w2[((o * 16 + ci) * 5 + dy) * 5 + dx] : 0.0f;
  long long m = llrint((double)wv * SC39);
#pragma unroll
  for (int j = 0; j < 5; j++) {
    int d = (int)((m + 128) & 255) - 128;
    AP[(size_t)((j * 20 + c) * 64 + lane) * 16 + e] = (signed char)d;
    m = (m - d) >> 8;
  }
}

// Stage 3 fused via exact i8 MFMA: conv2 + psp + spike + pool2 + psp + spike.
// (unchanged from R10: LDS u64 atomics, 1 barrier/group, 2 waves/SIMD)
__global__ __launch_bounds__(512, 2) void k_conv2v(const unsigned int* __restrict__ m2,
                                                   const signed char* __restrict__ AP,
                                                   unsigned char* __restrict__ s4) {
  __shared__ unsigned int maskW[2][2][192];          // [buf][slab tp][pos]; 3072 B
  __shared__ unsigned long long part[2][2][32][30];  // [parity][tp][R][col]; 30720 B
  int yp = blockIdx.x % 7, b = blockIdx.x / 7;
  int y0 = yp * 2;
  int tid = threadIdx.x;
  int w = tid >> 6, l = tid & 63;
  int tp = w & 1, kq = w >> 1;
  int col = l & 31, kh = l >> 5;
  int x = col % 14;
  unsigned int wmask = (col < 28) ? 31u : 0u;
  int half = (col >= 14) ? 1 : 0;
  const unsigned int* m2b = m2 + (size_t)b * T * 224;

  const i32x4* APv = (const i32x4*)AP;
  i32x4 Af[5][5];
#pragma unroll
  for (int j = 0; j < 5; j++)
#pragma unroll
    for (int q = 0; q < 5; q++)
      Af[j][q] = APv[(size_t)(j * 20 + 5 * kq + q) * 64 + l];

  int stPos[3] = {-1, -1, -1}, stIdx[3] = {-1, -1, -1};
  if (w < 2) {
#pragma unroll
    for (int pass = 0; pass < 3; pass++) {
      if (pass == 2 && l >= 32) continue;
      int e = pass * 64 + l;
      int H = e / 80, g = e % 80;
      int c = g >> 2, eh2 = (g >> 1) & 1, kh2 = g & 1;
      int kq2 = c / 5, q2 = c % 5;
      int ci = g / 5, dy = g % 5;
      int iy = y0 - 2 + H + dy;
      stPos[pass] = H * 96 + kh2 * 48 + kq2 * 12 + q2 * 2 + eh2;
      if (iy >= 0 && iy < 14) stIdx[pass] = ci * 14 + iy;
    }
  }

  int ct = tid - 256;
  bool chainAct = (ct >= 0) && (ct < 224);
  int po = (ct >= 0) ? ct / 7 : 0;
  int pp = (ct >= 0) ? ct % 7 : 0;
  double sg1[4] = {0, 0, 0, 0}, sg2[4] = {0, 0, 0, 0};
  double pq1 = 0.0, pq2 = 0.0;

  {
    unsigned long long* pf = &part[0][0][0][0];
    for (int e = tid; e < 2 * 2 * 32 * 30; e += 512) pf[e] = 0ull;
  }
  if (w < 2) {
#pragma unroll
    for (int pass = 0; pass < 3; pass++) {
      if (stPos[pass] < 0) continue;
      unsigned int v = 0;
      if (stIdx[pass] >= 0) v = m2b[(size_t)w * 224 + stIdx[pass]] << 2;
      maskW[0][w][stPos[pass]] = v;
    }
  }
  __syncthreads();

  for (int grp = 0; grp < 50; grp++) {
    int p = grp & 1, np = p ^ 1;

    unsigned int ld0 = 0, ld1 = 0, ld2 = 0;
    bool doStage = (w < 2) && (grp + 1 < 50);
    if (doStage) {
      size_t tb = (size_t)((grp + 1) * 2 + w) * 224;
      if (stIdx[0] >= 0) ld0 = m2b[tb + stIdx[0]] << 2;
      if (stIdx[1] >= 0) ld1 = m2b[tb + stIdx[1]] << 2;
      if (stIdx[2] >= 0) ld2 = m2b[tb + stIdx[2]] << 2;
    }

    {
      const uint4* mwv = (const uint4*)&maskW[p][tp][0];
      int base4 = half * 24 + kh * 12 + kq * 3;
      uint4 mk0 = mwv[base4 + 0], mk1 = mwv[base4 + 1], mk2 = mwv[base4 + 2];
      i32x16 ac0, ac1, ac2, ac3, ac4;
#pragma unroll
      for (int r = 0; r < 16; r++) { ac0[r] = 0; ac1[r] = 0; ac2[r] = 0; ac3[r] = 0; ac4[r] = 0; }
#pragma unroll
      for (int q = 0; q < 5; q++) {
        unsigned int ra = (q == 0) ? mk0.x : (q == 1) ? mk0.z : (q == 2) ? mk1.x
                         : (q == 3) ? mk1.z : mk2.x;
        unsigned int rb = (q == 0) ? mk0.y : (q == 1) ? mk0.w : (q == 2) ? mk1.y
                         : (q == 3) ? mk1.w : mk2.y;
        unsigned int a5 = (ra >> x) & wmask;
        unsigned int b5 = (rb >> x) & wmask;
        i32x4 bb;
        bb[0] = (int)(((a5 & 15u) * 0x204081u) & 0x01010101u);
        bb[1] = (int)((a5 >> 4) & 1u);
        bb[2] = (int)(((b5 & 15u) * 0x204081u) & 0x01010101u);
        bb[3] = (int)((b5 >> 4) & 1u);
        ac0 = __builtin_amdgcn_mfma_i32_32x32x32_i8(Af[0][q], bb, ac0, 0, 0, 0);
        ac1 = __builtin_amdgcn_mfma_i32_32x32x32_i8(Af[1][q], bb, ac1, 0, 0, 0);
        ac2 = __builtin_amdgcn_mfma_i32_32x32x32_i8(Af[2][q], bb, ac2, 0, 0, 0);
        ac3 = __builtin_amdgcn_mfma_i32_32x32x32_i8(Af[3][q], bb, ac3, 0, 0, 0);
        ac4 = __builtin_amdgcn_mfma_i32_32x32x32_i8(Af[4][q], bb, ac4, 0, 0, 0);
      }
      if (col < 28) {
#pragma unroll
        for (int r = 0; r < 16; r++) {
          int R = (r & 3) + 8 * (r >> 2) + 4 * kh;
          int c01 = ac1[r] * 256 + ac0[r];
          int c23 = ac3[r] * 256 + ac2[r];
          long long S = (long long)ac4[r] * 4294967296LL +
                        (long long)c23 * 65536LL + (long long)c01;
          atomicAdd(&part[p][tp][R][col], (unsigned long long)S);
        }
      }
    }

    if (doStage) {
      if (stPos[0] >= 0) maskW[np][w][stPos[0]] = ld0;
      if (stPos[1] >= 0) maskW[np][w][stPos[1]] = ld1;
      if (stPos[2] >= 0) maskW[np][w][stPos[2]] = ld2;
    }
    __syncthreads();  // single barrier: part[p] sums complete + masks staged

    if (chainAct) {
#pragma unroll
      for (int g = 0; g < 2; g++) {
        unsigned long long v0 = part[p][g][po][2 * pp];
        unsigned long long v1 = part[p][g][po][2 * pp + 1];
        unsigned long long v2 = part[p][g][po][14 + 2 * pp];
        unsigned long long v3 = part[p][g][po][15 + 2 * pp];
        part[p][g][po][2 * pp] = 0ull;
        part[p][g][po][2 * pp + 1] = 0ull;
        part[p][g][po][14 + 2 * pp] = 0ull;
        part[p][g][po][15 + 2 * pp] = 0ull;
        double c0 = (double)(long long)v0 * INV39;
        double c1 = (double)(long long)v1 * INV39;
        double c2 = (double)(long long)v2 * INV39;
        double c3 = (double)(long long)v3 * INV39;
        sg1[0] = c0 + A1 * sg1[0]; sg2[0] = sg1[0] + A1 * sg2[0];
        sg1[1] = c1 + A1 * sg1[1]; sg2[1] = sg1[1] + A1 * sg2[1];
        sg1[2] = c2 + A1 * sg1[2]; sg2[2] = sg1[2] + A1 * sg2[2];
        sg1[3] = c3 + A1 * sg1[3]; sg2[3] = sg1[3] + A1 * sg2[3];
        int sum = ((CE * (sg2[0] - sg1[0]) >= 1.0) ? 1 : 0)
                + ((CE * (sg2[1] - sg1[1]) >= 1.0) ? 1 : 0)
                + ((CE * (sg2[2] - sg1[2]) >= 1.0) ? 1 : 0)
                + ((CE * (sg2[3] - sg1[3]) >= 1.0) ? 1 : 0);
        double s = 1.1 * (double)sum;
        pq1 = s + A1 * pq1;
        pq2 = pq1 + A1 * pq2;
        s4[(size_t)(b * T + grp * 2 + g) * 1568 + po * 49 + yp * 7 + pp] =
            (CE * (pq2 - pq1) >= 1.0) ? 1 : 0;
      }
    }
  }
}

// dense1 weight limbs: 5 signed base-256 digits of round(wf1*2^39), packed as
// MFMA B-fragments with logical k = kh*16 + e.  (unchanged)
__global__ void k_limbs2(const float* __restrict__ wf1, signed char* __restrict__ BP) {
  int i = blockIdx.x * 256 + threadIdx.x;
  if (i >= 13 * 5 * 49 * 64) return;
  int lane = i & 63;
  int fi = i >> 6;
  int c = fi % 49;
  int j = (fi / 49) % 5;
  int ot = fi / 245;
  int o = ot * 32 + (lane & 31);
  int kb = 32 * c + (lane >> 5) * 16;
  int wd[4] = {0, 0, 0, 0};
#pragma unroll
  for (int e = 0; e < 16; e++) {
    float wv = (o < 410) ? wf1[(size_t)o * 1568 + kb + e] : 0.0f;
    long long m = llrint((double)wv * SC39);
    int d = 0;
    for (int jj = 0; jj <= j; jj++) {
      d = (int)((m + 128) & 255) - 128;
      m = (m - d) >> 8;
    }
    wd[e >> 2] |= (d & 255) << ((e & 3) * 8);
  }
  i32x4 v;
  v[0] = wd[0]; v[1] = wd[1]; v[2] = wd[2]; v[3] = wd[3];
  *(i32x4*)(BP + (size_t)i * 16) = v;
}

// dense2 weight limbs: 5 signed base-256 digits of round(wf2*2^39), packed as
// MFMA B-fragments.  fi = j*13 + c; o = lane&31 (0 for o>=10);
// k = 32c + (lane>>5)*16 + e, zero-padded past 410.
__global__ void k_limbs3(const float* __restrict__ wf2, signed char* __restrict__ BP2) {
  int i = blockIdx.x * 256 + threadIdx.x;
  if (i >= 5 * 13 * 64) return;
  int lane = i & 63;
  int fi = i >> 6;
  int c = fi % 13;
  int j = fi / 13;
  int o = lane & 31;
  int kb = 32 * c + (lane >> 5) * 16;
  int wd[4] = {0, 0, 0, 0};
#pragma unroll
  for (int e = 0; e < 16; e++) {
    int k = kb + e;
    float wv = (o < 10 && k < 410) ? wf2[o * 410 + k] : 0.0f;
    long long m = llrint((double)wv * SC39);
    int d = 0;
    for (int jj = 0; jj <= j; jj++) {
      d = (int)((m + 128) & 255) - 128;
      m = (m - d) >> 8;
    }
    wd[e >> 2] |= (d & 255) << ((e & 3) * 8);
  }
  i32x4 v;
  v[0] = wd[0]; v[1] = wd[1]; v[2] = wd[2]; v[3] = wd[3];
  *(i32x4*)(BP2 + (size_t)i * 16) = v;
}

// Stage 5a: dense1 as exact i8-limb MFMA GEMM.  (unchanged)
__global__ __launch_bounds__(256) void k_dense1m(const unsigned char* __restrict__ s4,
                                                 const signed char* __restrict__ BP,
                                                 double* __restrict__ d5) {
  int ot = blockIdx.y;
  int w = threadIdx.x >> 6, l = threadIdx.x & 63;
  int col = l & 31, kh = l >> 5;
  int btTile = blockIdx.x * 4 + w;
  const unsigned char* arow = s4 + (size_t)(btTile * 32 + col) * 1568 + kh * 16;
  const i32x4* bpv = (const i32x4*)BP + (size_t)ot * 245 * 64 + l;
  i32x16 acc0, acc1, acc2, acc3, acc4;
#pragma unroll
  for (int r = 0; r < 16; r++) {
    acc0[r] = 0; acc1[r] = 0; acc2[r] = 0; acc3[r] = 0; acc4[r] = 0;
  }
  for (int c = 0; c < 49; c++) {
    i32x4 a = *(const i32x4*)(arow + 32 * c);
    i32x4 b0 = bpv[(0 * 49 + c) * 64];
    i32x4 b1 = bpv[(1 * 49 + c) * 64];
    i32x4 b2 = bpv[(2 * 49 + c) * 64];
    i32x4 b3 = bpv[(3 * 49 + c) * 64];
    i32x4 b4 = bpv[(4 * 49 + c) * 64];
    acc0 = __builtin_amdgcn_mfma_i32_32x32x32_i8(a, b0, acc0, 0, 0, 0);
    acc1 = __builtin_amdgcn_mfma_i32_32x32x32_i8(a, b1, acc1, 0, 0, 0);
    acc2 = __builtin_amdgcn_mfma_i32_32x32x32_i8(a, b2, acc2, 0, 0, 0);
    acc3 = __builtin_amdgcn_mfma_i32_32x32x32_i8(a, b3, acc3, 0, 0, 0);
    acc4 = __builtin_amdgcn_mfma_i32_32x32x32_i8(a, b4, acc4, 0, 0, 0);
  }
  int o = ot * 32 + col;
  if (o < 410) {
#pragma unroll
    for (int r = 0; r < 16; r++) {
      int R = (r & 3) + 8 * (r >> 2) + 4 * kh;
      double v = ((((double)acc4[r] * 256.0 + (double)acc3[r]) * 256.0 +
                   (double)acc2[r]) * 256.0 + (double)acc1[r]) * 256.0 + (double)acc0[r];
      d5[(size_t)(btTile * 32 + R) * 410 + o] = v * INV39;
    }
  }
}

// Stage 5b: psp + spike over dense1 output.  One thread per (b,o); o>=410
// zeroes the s5 pad (stride 416 for dense2m's 16B A-loads).
__global__ void k_psp5(const double* __restrict__ d5, unsigned char* __restrict__ s5) {
  int tid = blockIdx.x * 64 + threadIdx.x;
  if (tid >= B * 416) return;
  int o = tid % 416, b = tid / 416;
  if (o >= 410) {
    for (int t = 0; t < T; t++) s5[(size_t)(b * T + t) * 416 + o] = 0;
    return;
  }
  double g1 = 0.0, g2 = 0.0;
  for (int t = 0; t < T; t++) {
    double s = d5[(size_t)(b * T + t) * 410 + o];
    g1 = s + A1 * g1;
    g2 = g1 + A1 * g2;
    s5[(size_t)(b * T + t) * 416 + o] = (CE * (g2 - g1) >= 1.0) ? 1 : 0;
  }
}

// Stage 6a: dense2 as exact i8-limb MFMA GEMM.  M=3200 (bt), N=10 (pad 32),
// K=410 (pad 416): 13 chunks x 5 limbs = 65 MFMAs/wave; grid 25 x 4 waves.
__global__ __launch_bounds__(256) void k_dense2m(const unsigned char* __restrict__ s5,
                                                 const signed char* __restrict__ BP2,
                                                 double* __restrict__ d6) {
  int w = threadIdx.x >> 6, l = threadIdx.x & 63;
  int col = l & 31, kh = l >> 5;
  int btTile = blockIdx.x * 4 + w;
  const unsigned char* arow = s5 + (size_t)(btTile * 32 + col) * 416 + kh * 16;
  const i32x4* bpv = (const i32x4*)BP2 + l;
  i32x16 acc0, acc1, acc2, acc3, acc4;
#pragma unroll
  for (int r = 0; r < 16; r++) {
    acc0[r] = 0; acc1[r] = 0; acc2[r] = 0; acc3[r] = 0; acc4[r] = 0;
  }
#pragma unroll
  for (int c = 0; c < 13; c++) {
    i32x4 a = *(const i32x4*)(arow + 32 * c);
    i32x4 b0 = bpv[(0 * 13 + c) * 64];
    i32x4 b1 = bpv[(1 * 13 + c) * 64];
    i32x4 b2 = bpv[(2 * 13 + c) * 64];
    i32x4 b3 = bpv[(3 * 13 + c) * 64];
    i32x4 b4 = bpv[(4 * 13 + c) * 64];
    acc0 = __builtin_amdgcn_mfma_i32_32x32x32_i8(a, b0, acc0, 0, 0, 0);
    acc1 = __builtin_amdgcn_mfma_i32_32x32x32_i8(a, b1, acc1, 0, 0, 0);
    acc2 = __builtin_amdgcn_mfma_i32_32x32x32_i8(a, b2, acc2, 0, 0, 0);
    acc3 = __builtin_amdgcn_mfma_i32_32x32x32_i8(a, b3, acc3, 0, 0, 0);
    acc4 = __builtin_amdgcn_mfma_i32_32x32x32_i8(a, b4, acc4, 0, 0, 0);
  }
  if (col < 10) {
#pragma unroll
    for (int r = 0; r < 16; r++) {
      int R = (r & 3) + 8 * (r >> 2) + 4 * kh;
      double v = ((((double)acc4[r] * 256.0 + (double)acc3[r]) * 256.0 +
                   (double)acc2[r]) * 256.0 + (double)acc1[r]) * 256.0 + (double)acc0[r];
      d6[(size_t)(btTile * 32 + R) * 10 + col] = v * INV39;
    }
  }
}

// Stage 6b: final psp + spike -> d_out [b][o][t] f32.
__global__ void k_psp6(const double* __restrict__ d6, float* __restrict__ out) {
  int tid = blockIdx.x * 64 + threadIdx.x;
  if (tid >= B * 10) return;
  int o = tid % 10, b = tid / 10;
  double g1 = 0.0, g2 = 0.0;
  for (int t = 0; t < T; t++) {
    double s = d6[(size_t)(b * T + t) * 10 + o];
    g1 = s + A1 * g1;
    g2 = g1 + A1 * g2;
    out[(size_t)b * 1000 + o * 100 + t] = (CE * (g2 - g1) >= 1.0) ? 1.0f : 0.0f;
  }
}

extern "C" void kernel_launch(void* const* d_in, const int* in_sizes, int n_in,
                              void* d_out, int out_size, void* d_ws, size_t ws_size,
                              hipStream_t stream) {
  const float* img = (const float*)d_in[0];
  const float* ru = (const float*)d_in[1];
  const float* w1 = (const float*)d_in[2];
  const float* w2 = (const float*)d_in[3];
  const float* wf1 = (const float*)d_in[4];
  const float* wf2 = (const float*)d_in[5];

  unsigned char* ws = (unsigned char*)d_ws;
  unsigned int* m1 = (unsigned int*)(ws + OFF_M1);
  unsigned int* m2 = (unsigned int*)(ws + OFF_M2);
  unsigned char* s4 = ws + OFF_S4;
  double* d5 = (double*)(ws + OFF_D5);
  unsigned char* s5 = ws + OFF_S5;
  double* d6 = (double*)(ws + OFF_D6);
  signed char* AP = (signed char*)(ws + OFF_AP);  // aliases d5 (freed before dense1m)
  signed char* BP = (signed char*)(ws + OFF_BP);
  signed char* BP2 = (signed char*)(ws + OFF_BP2);
  float* out = (float*)d_out;

  k_encode_pack<<<(B * 28 * T + 255) / 256, 256, 0, stream>>>(img, ru, m1);
  k_limbs<<<(32 * 80 * 8 + 255) / 256, 256, 0, stream>>>(w2, AP);
  k_limbs2<<<(13 * 5 * 49 * 64 + 255) / 256, 256, 0, stream>>>(wf1, BP);
  k_limbs3<<<(5 * 13 * 64 + 255) / 256, 256, 0, stream>>>(wf2, BP2);
  k_conv1w<<<B * 16, 256, 0, stream>>>(m1, w1, m2);
  k_conv2v<<<B * 7, 512, 0, stream>>>(m2, AP, s4);
  k_dense1m<<<dim3(25, 13), 256, 0, stream>>>(s4, BP, d5);
  k_psp5<<<(B * 416 + 63) / 64, 64, 0, stream>>>(d5, s5);
  k_dense2m<<<25, 256, 0, stream>>>(s5, BP2, d6);
  k_psp6<<<(B * 10 + 63) / 64, 64, 0, stream>>>(d6, out);
}